// Round 3
// baseline (397.985 us; speedup 1.0000x reference)
//
#include <hip/hip_runtime.h>
#include <math.h>

#define NUM_C 9
constexpr float W_BASE = 0.1f / 9.0f;     // 0.0111111
constexpr float W_MAIN = 0.7f;            // 1 - 0.1 - 0.2

constexpr int THREADS = 256;
constexpr int ROWS_PER_BLOCK = 1024;                       // 4 rows/thread
constexpr int VECS_PER_BLOCK = ROWS_PER_BLOCK * NUM_C / 4; // 2304 float4
constexpr int VECS_PER_WAVE = VECS_PER_BLOCK / 4;          // 576
constexpr int CALLS_PER_WAVE = VECS_PER_WAVE / 64;         // 9

__device__ __forceinline__ void async_copy16(const float4* g, float4* l) {
    __builtin_amdgcn_global_load_lds(
        (const __attribute__((address_space(1))) void*)g,
        (__attribute__((address_space(3))) void*)l,
        16 /*bytes*/, 0 /*offset*/, 0 /*aux*/);
}

// d_ws layout: [0..3] uint counter (memset to 0 pre-launch); [16..] float partials
__global__ __launch_bounds__(THREADS, 4) void ccel_main(
    const float* __restrict__ logits,
    const int* __restrict__ targets,
    unsigned* __restrict__ counter,
    float* __restrict__ partials,
    float* __restrict__ out,
    int nRows, int nFullBlocks, int nBlocks, float invBatch)
{
    __shared__ float4 lds4[VECS_PER_BLOCK];   // 36 KB -> 4 blocks/CU
    __shared__ float wave_sums[THREADS / 64];
    __shared__ int is_last;

    const int tid = threadIdx.x;
    const int wave = tid >> 6;
    const int lane = tid & 63;
    const long long vecBase = (long long)blockIdx.x * VECS_PER_BLOCK;
    const float4* gv = (const float4*)logits + vecBase;

    // Issue targets load BEFORE the barrier so its latency hides under the
    // staging drain (the pre-barrier s_waitcnt vmcnt(0) covers it).
    const int myRow = blockIdx.x * ROWS_PER_BLOCK + tid * 4;
    int4 t4 = {0, 0, 0, 0};
    if (myRow < nRows) t4 = ((const int4*)targets)[myRow >> 2];

    if (blockIdx.x < nFullBlocks) {
        // Direct global->LDS DMA, 16B per lane, linear layout (wave-uniform base).
        const float4* src = gv + wave * VECS_PER_WAVE;
        float4* dst = lds4 + wave * VECS_PER_WAVE;
#pragma unroll
        for (int i = 0; i < CALLS_PER_WAVE; i++) {
            async_copy16(src + i * 64 + lane, dst + i * 64);
        }
    } else {
        // Tail block: guarded VGPR path.
        const long long totalVecs = ((long long)nRows * NUM_C) / 4;
        for (int i = tid; i < VECS_PER_BLOCK; i += THREADS) {
            if (vecBase + i < totalVecs) lds4[i] = gv[i];
        }
    }
    __syncthreads();   // s_waitcnt vmcnt(0) covers async staging + t4

    float acc = 0.0f;

    if (myRow < nRows) {   // tail rows come in whole multiples of 4 per thread
        const int tg[4] = {t4.x, t4.y, t4.z, t4.w};

        // 36 consecutive floats (4 rows) via 9 ds_read_b128
        float x[36];
        float4* xv = (float4*)x;
#pragma unroll
        for (int i = 0; i < 9; i++) xv[i] = lds4[tid * 9 + i];

#pragma unroll
        for (int k = 0; k < 4; k++) {
            const float* xr = x + k * NUM_C;
            const int t = tg[k];

            float m = xr[0];
#pragma unroll
            for (int j = 1; j < NUM_C; j++) m = fmaxf(m, xr[j]);

            float sum = 0.0f, xt = 0.0f;
#pragma unroll
            for (int j = 0; j < NUM_C; j++) {
                sum += xr[j];
                xt = (t == j) ? xr[j] : xt;
            }

            // G(t) = sum_{j>t} 2^(t-j) x[j] via backward halving scan
            float g = 0.0f, gt = 0.0f;
#pragma unroll
            for (int j = NUM_C - 1; j >= 1; j--) {
                g = 0.5f * (xr[j] + g);
                gt = (t == j - 1) ? g : gt;
            }

            float es = 0.0f;
#pragma unroll
            for (int j = 0; j < NUM_C; j++) es += __expf(xr[j] - m);
            const float lse = m + __logf(es);

            const float S = 0.98888889f - 0.2f * ldexpf(1.0f, t - 8);
            const float weighted = W_BASE * sum + (W_MAIN - W_BASE) * xt + 0.2f * gt;
            acc += lse - weighted * __builtin_amdgcn_rcpf(S);
        }
    }

    // wave reduce (64 lanes)
#pragma unroll
    for (int off = 32; off > 0; off >>= 1)
        acc += __shfl_down(acc, off, 64);

    if (lane == 0) wave_sums[wave] = acc;
    __syncthreads();
    if (tid == 0) {
        float bsum = 0.0f;
#pragma unroll
        for (int w = 0; w < THREADS / 64; w++) bsum += wave_sums[w];
        partials[blockIdx.x] = bsum;
        __threadfence();                              // release partial
        unsigned old = atomicAdd(counter, 1u);        // device scope
        is_last = (old == (unsigned)(nBlocks - 1)) ? 1 : 0;
    }
    __syncthreads();

    if (is_last) {
        __threadfence();                              // acquire all partials
        double dacc = 0.0;
        for (int i = tid; i < nBlocks; i += THREADS)
            dacc += (double)partials[i];
#pragma unroll
        for (int off = 32; off > 0; off >>= 1)
            dacc += __shfl_down(dacc, off, 64);
        __shared__ double dsum[THREADS / 64];
        if (lane == 0) dsum[wave] = dacc;
        __syncthreads();
        if (tid == 0) {
            double total = 0.0;
#pragma unroll
            for (int w = 0; w < THREADS / 64; w++) total += dsum[w];
            out[0] = (float)(total * (double)invBatch);
        }
    }
}

extern "C" void kernel_launch(void* const* d_in, const int* in_sizes, int n_in,
                              void* d_out, int out_size, void* d_ws, size_t ws_size,
                              hipStream_t stream) {
    const float* logits = (const float*)d_in[0];
    const int* targets = (const int*)d_in[1];
    const int nRows = in_sizes[1];                 // 4,000,000

    unsigned* counter = (unsigned*)d_ws;
    float* partials = (float*)((char*)d_ws + 16);
    const int nBlocks = (nRows + ROWS_PER_BLOCK - 1) / ROWS_PER_BLOCK;   // 3907
    const long long totalVecs = ((long long)nRows * NUM_C) / 4;
    const int nFullBlocks = (int)(totalVecs / VECS_PER_BLOCK);           // 3906

    hipMemsetAsync(counter, 0, sizeof(unsigned), stream);  // graph-capturable memset node
    ccel_main<<<nBlocks, THREADS, 0, stream>>>(logits, targets, counter, partials,
                                               (float*)d_out, nRows, nFullBlocks,
                                               nBlocks, 1.0f / (float)nRows);
}

// Round 4
// 220.435 us; speedup vs baseline: 1.8055x; 1.8055x over previous
//
#include <hip/hip_runtime.h>
#include <math.h>

#define NUM_C 9
constexpr float W_BASE = 0.1f / 9.0f;     // 0.0111111
constexpr float W_MAIN = 0.7f;            // 1 - 0.1 - 0.2

constexpr int THREADS = 256;
constexpr int ROWS_PER_BLOCK = 1024;                       // 4 rows/thread
constexpr int VECS_PER_BLOCK = ROWS_PER_BLOCK * NUM_C / 4; // 2304 float4
constexpr int VECS_PER_WAVE = VECS_PER_BLOCK / 4;          // 576
constexpr int CALLS_PER_WAVE = VECS_PER_WAVE / 64;         // 9

__device__ __forceinline__ void async_copy16(const float4* g, float4* l) {
    __builtin_amdgcn_global_load_lds(
        (const __attribute__((address_space(1))) void*)g,
        (__attribute__((address_space(3))) void*)l,
        16 /*bytes*/, 0 /*offset*/, 0 /*aux*/);
}

// NOTE (R3 lesson): no __threadfence() anywhere — device-scope fences emit
// per-L2 writeback/invalidate on gfx950; 3907 of them serialized the memory
// system (250 µs kernel at 4% HBM). Cross-block combining goes through
// atomicAdd only (device-coherent without cache flushes).
__global__ __launch_bounds__(THREADS, 4) void ccel_main(
    const float* __restrict__ logits,
    const int* __restrict__ targets,
    float* __restrict__ out,          // zeroed by memset node before this kernel
    int nRows, int nFullBlocks, float invBatch)
{
    __shared__ float4 lds4[VECS_PER_BLOCK];   // 36 KB -> 4 blocks/CU
    __shared__ float wave_sums[THREADS / 64];

    const int tid = threadIdx.x;
    const int wave = tid >> 6;
    const int lane = tid & 63;
    const long long vecBase = (long long)blockIdx.x * VECS_PER_BLOCK;
    const float4* gv = (const float4*)logits + vecBase;

    // Targets load issued BEFORE the barrier: its latency hides under the
    // staging drain (pre-barrier s_waitcnt vmcnt(0) covers it).
    const int myRow = blockIdx.x * ROWS_PER_BLOCK + tid * 4;
    int4 t4 = {0, 0, 0, 0};
    if (myRow < nRows) t4 = ((const int4*)targets)[myRow >> 2];

    if (blockIdx.x < nFullBlocks) {
        // Direct global->LDS DMA, 16B/lane, linear layout (wave-uniform base).
        const float4* src = gv + wave * VECS_PER_WAVE;
        float4* dst = lds4 + wave * VECS_PER_WAVE;
#pragma unroll
        for (int i = 0; i < CALLS_PER_WAVE; i++) {
            async_copy16(src + i * 64 + lane, dst + i * 64);
        }
    } else {
        // Tail block: guarded VGPR path.
        const long long totalVecs = ((long long)nRows * NUM_C) / 4;
        for (int i = tid; i < VECS_PER_BLOCK; i += THREADS) {
            if (vecBase + i < totalVecs) lds4[i] = gv[i];
        }
    }
    __syncthreads();   // drains vmcnt for async staging + t4

    float acc = 0.0f;

    if (myRow < nRows) {   // tail rows come in whole multiples of 4 per thread
        const int tg[4] = {t4.x, t4.y, t4.z, t4.w};

        // 36 consecutive floats (4 rows) via 9 ds_read_b128
        float x[36];
        float4* xv = (float4*)x;
#pragma unroll
        for (int i = 0; i < 9; i++) xv[i] = lds4[tid * 9 + i];

#pragma unroll
        for (int k = 0; k < 4; k++) {
            const float* xr = x + k * NUM_C;
            const int t = tg[k];

            float m = xr[0];
#pragma unroll
            for (int j = 1; j < NUM_C; j++) m = fmaxf(m, xr[j]);

            float sum = 0.0f, xt = 0.0f;
#pragma unroll
            for (int j = 0; j < NUM_C; j++) {
                sum += xr[j];
                xt = (t == j) ? xr[j] : xt;
            }

            // G(t) = sum_{j>t} 2^(t-j) x[j] via backward halving scan
            float g = 0.0f, gt = 0.0f;
#pragma unroll
            for (int j = NUM_C - 1; j >= 1; j--) {
                g = 0.5f * (xr[j] + g);
                gt = (t == j - 1) ? g : gt;
            }

            float es = 0.0f;
#pragma unroll
            for (int j = 0; j < NUM_C; j++) es += __expf(xr[j] - m);
            const float lse = m + __logf(es);

            const float S = 0.98888889f - 0.2f * ldexpf(1.0f, t - 8);
            const float weighted = W_BASE * sum + (W_MAIN - W_BASE) * xt + 0.2f * gt;
            acc += lse - weighted * __builtin_amdgcn_rcpf(S);
        }
    }

    // wave reduce (64 lanes)
#pragma unroll
    for (int off = 32; off > 0; off >>= 1)
        acc += __shfl_down(acc, off, 64);

    if (lane == 0) wave_sums[wave] = acc;
    __syncthreads();
    if (tid == 0) {
        float bsum = 0.0f;
#pragma unroll
        for (int w = 0; w < THREADS / 64; w++) bsum += wave_sums[w];
        // One device-scope float atomic per block; no fence, no finish kernel.
        atomicAdd(out, bsum * invBatch);
    }
}

extern "C" void kernel_launch(void* const* d_in, const int* in_sizes, int n_in,
                              void* d_out, int out_size, void* d_ws, size_t ws_size,
                              hipStream_t stream) {
    const float* logits = (const float*)d_in[0];
    const int* targets = (const int*)d_in[1];
    const int nRows = in_sizes[1];                 // 4,000,000

    const int nBlocks = (nRows + ROWS_PER_BLOCK - 1) / ROWS_PER_BLOCK;   // 3907
    const long long totalVecs = ((long long)nRows * NUM_C) / 4;
    const int nFullBlocks = (int)(totalVecs / VECS_PER_BLOCK);           // 3906

    hipMemsetAsync(d_out, 0, sizeof(float), stream);   // graph-capturable node
    ccel_main<<<nBlocks, THREADS, 0, stream>>>(logits, targets, (float*)d_out,
                                               nRows, nFullBlocks,
                                               1.0f / (float)nRows);
}

// Round 5
// 213.197 us; speedup vs baseline: 1.8667x; 1.0339x over previous
//
#include <hip/hip_runtime.h>
#include <math.h>

#define NUM_C 9
constexpr float W_BASE = 0.1f / 9.0f;     // 0.0111111
constexpr float W_MAIN = 0.7f;            // 1 - 0.1 - 0.2

constexpr int THREADS = 256;
constexpr int ROWS_PER_BLOCK = 1024;                       // 4 rows/thread
constexpr int VECS_PER_BLOCK = ROWS_PER_BLOCK * NUM_C / 4; // 2304 float4
constexpr int VECS_PER_WAVE = VECS_PER_BLOCK / 4;          // 576
constexpr int CALLS_PER_WAVE = VECS_PER_WAVE / 64;         // 9

__device__ __forceinline__ void async_copy16(const float4* g, float4* l) {
    __builtin_amdgcn_global_load_lds(
        (const __attribute__((address_space(1))) void*)g,
        (__attribute__((address_space(3))) void*)l,
        16 /*bytes*/, 0 /*offset*/, 0 /*aux*/);
}

// R3 lesson: NO __threadfence() — device-scope fences emit per-L2
// writeback/invalidate on gfx950; at 3907 blocks that serialized the memory
// system (250 µs @ 4% HBM). Two-kernel reduction (R2-proven) instead.
__global__ __launch_bounds__(THREADS, 4) void ccel_main(
    const float* __restrict__ logits,
    const int* __restrict__ targets,
    float* __restrict__ partials,
    int nRows, int nFullBlocks)
{
    __shared__ float4 lds4[VECS_PER_BLOCK];   // 36 KB -> 4 blocks/CU
    __shared__ float wave_sums[THREADS / 64];

    const int tid = threadIdx.x;
    const int wave = tid >> 6;
    const int lane = tid & 63;
    const long long vecBase = (long long)blockIdx.x * VECS_PER_BLOCK;
    const float4* gv = (const float4*)logits + vecBase;

    // Targets load issued BEFORE the barrier: latency hides under the staging
    // drain (the pre-barrier s_waitcnt vmcnt(0) covers it).
    const int myRow = blockIdx.x * ROWS_PER_BLOCK + tid * 4;
    int4 t4 = {0, 0, 0, 0};
    if (myRow < nRows) t4 = ((const int4*)targets)[myRow >> 2];

    if (blockIdx.x < nFullBlocks) {
        // Direct global->LDS DMA, 16B/lane, linear layout (wave-uniform base).
        const float4* src = gv + wave * VECS_PER_WAVE;
        float4* dst = lds4 + wave * VECS_PER_WAVE;
#pragma unroll
        for (int i = 0; i < CALLS_PER_WAVE; i++) {
            async_copy16(src + i * 64 + lane, dst + i * 64);
        }
    } else {
        // Tail block: guarded VGPR path.
        const long long totalVecs = ((long long)nRows * NUM_C) / 4;
        for (int i = tid; i < VECS_PER_BLOCK; i += THREADS) {
            if (vecBase + i < totalVecs) lds4[i] = gv[i];
        }
    }
    __syncthreads();   // drains vmcnt for async staging + t4

    float acc = 0.0f;

    if (myRow < nRows) {   // tail rows come in whole multiples of 4 per thread
        const int tg[4] = {t4.x, t4.y, t4.z, t4.w};

        // 36 consecutive floats (4 rows) via 9 ds_read_b128
        float x[36];
        float4* xv = (float4*)x;
#pragma unroll
        for (int i = 0; i < 9; i++) xv[i] = lds4[tid * 9 + i];

#pragma unroll
        for (int k = 0; k < 4; k++) {
            const float* xr = x + k * NUM_C;
            const int t = tg[k];

            float m = xr[0];
#pragma unroll
            for (int j = 1; j < NUM_C; j++) m = fmaxf(m, xr[j]);

            float sum = 0.0f, xt = 0.0f;
#pragma unroll
            for (int j = 0; j < NUM_C; j++) {
                sum += xr[j];
                xt = (t == j) ? xr[j] : xt;
            }

            // G(t) = sum_{j>t} 2^(t-j) x[j] via backward halving scan
            float g = 0.0f, gt = 0.0f;
#pragma unroll
            for (int j = NUM_C - 1; j >= 1; j--) {
                g = 0.5f * (xr[j] + g);
                gt = (t == j - 1) ? g : gt;
            }

            float es = 0.0f;
#pragma unroll
            for (int j = 0; j < NUM_C; j++) es += __expf(xr[j] - m);
            const float lse = m + __logf(es);

            const float S = 0.98888889f - 0.2f * ldexpf(1.0f, t - 8);
            const float weighted = W_BASE * sum + (W_MAIN - W_BASE) * xt + 0.2f * gt;
            acc += lse - weighted * __builtin_amdgcn_rcpf(S);
        }
    }

    // wave reduce (64 lanes)
#pragma unroll
    for (int off = 32; off > 0; off >>= 1)
        acc += __shfl_down(acc, off, 64);

    if (lane == 0) wave_sums[wave] = acc;
    __syncthreads();
    if (tid == 0) {
        float bsum = 0.0f;
#pragma unroll
        for (int w = 0; w < THREADS / 64; w++) bsum += wave_sums[w];
        partials[blockIdx.x] = bsum;
    }
}

__global__ __launch_bounds__(1024) void ccel_finish(
    const float* __restrict__ partials,
    int n,
    float* __restrict__ out,
    float invBatch)
{
    double acc = 0.0;
    for (int i = threadIdx.x; i < n; i += 1024)
        acc += (double)partials[i];

#pragma unroll
    for (int off = 32; off > 0; off >>= 1)
        acc += __shfl_down(acc, off, 64);

    __shared__ double wsum[16];
    if ((threadIdx.x & 63) == 0) wsum[threadIdx.x >> 6] = acc;
    __syncthreads();
    if (threadIdx.x == 0) {
        double total = 0.0;
#pragma unroll
        for (int w = 0; w < 16; w++) total += wsum[w];
        out[0] = (float)(total * (double)invBatch);
    }
}

extern "C" void kernel_launch(void* const* d_in, const int* in_sizes, int n_in,
                              void* d_out, int out_size, void* d_ws, size_t ws_size,
                              hipStream_t stream) {
    const float* logits = (const float*)d_in[0];
    const int* targets = (const int*)d_in[1];
    const int nRows = in_sizes[1];                 // 4,000,000

    float* partials = (float*)d_ws;
    const int nBlocks = (nRows + ROWS_PER_BLOCK - 1) / ROWS_PER_BLOCK;   // 3907
    const long long totalVecs = ((long long)nRows * NUM_C) / 4;
    const int nFullBlocks = (int)(totalVecs / VECS_PER_BLOCK);           // 3906

    ccel_main<<<nBlocks, THREADS, 0, stream>>>(logits, targets, partials,
                                               nRows, nFullBlocks);
    ccel_finish<<<1, 1024, 0, stream>>>(partials, nBlocks, (float*)d_out,
                                        1.0f / (float)nRows);
}